// Round 3
// baseline (1112.814 us; speedup 1.0000x reference)
//
#include <hip/hip_runtime.h>
#include <math.h>

// ---------------------------------------------------------------------------
// CrossAttentionLayer_convk3s2 — FP32 in/out, bf16 MFMA internally.
// R3: kmain restructured:
//   - coarse C3 (9 barriers + 144 u16 gathers) -> vc-in-registers across taps
//     + swizzled vcT LDS buffer + single PV MFMA phase (3 barriers)
//   - kffn FUSED into kmain (per-block 10-row FFN, fine/coarse dual GEMMs,
//     wave-parallel LN) — removes kernel + 42 MB p.out round-trip
//   - k0a + ktrans merged into kprep (one launch fewer)
// Launches: kprep(9) -> kfold(18) -> kmain(4096).
// ---------------------------------------------------------------------------

typedef short   mfrag  __attribute__((ext_vector_type(8)));   // 8 x bf16 bits
typedef float   floatx4 __attribute__((ext_vector_type(4)));
typedef unsigned short us4 __attribute__((ext_vector_type(4)));
typedef unsigned short us8 __attribute__((ext_vector_type(8)));

#define LL   216     // 12*18 tokens
#define LC   54      // 6*9 coarse positions
#define TP1  136     // pitch (ushorts) for 128-col LDS rows (272B)
#define TP2  72      // pitch (ushorts) for 64-col LDS rows

__device__ __forceinline__ float b2f(unsigned short u){
  return __uint_as_float(((unsigned int)u) << 16);
}
__device__ __forceinline__ unsigned short f2b(float f){
  unsigned int x = __float_as_uint(f);
  return (unsigned short)((x + 0x7fffu + ((x >> 16) & 1u)) >> 16);
}
__device__ __forceinline__ floatx4 mfma16(mfrag a, mfrag b, floatx4 c){
  return __builtin_amdgcn_mfma_f32_16x16x32_bf16(a, b, c, 0, 0, 0);
}
__device__ __forceinline__ mfrag zfrag(){ mfrag z = {0,0,0,0,0,0,0,0}; return z; }

union F8 { unsigned short u[8]; mfrag v; };

struct Par {
  const float *query,*tgt,*ln1g,*ln1b,*ln2g,*ln2b,*wq,*bq,*wk,*wv,*bv,
              *wp,*bp,*f1w,*f1b,*f2w,*f2b,*cw,*cb;
  const float *ln1cg,*ln1cb,*ln2cg,*ln2cb,*wqc,*bqc,*wkc,*wvc,*bvc,
              *wpc,*bpc,*f1cw,*f1cb,*f2cw,*f2cb;
  unsigned short *U;      // [48][128] bf16: fine score vectors (0.25 * wk @ q_head)
  float          *uc;     // [32][128] f32: coarse score vectors pre-conv-fold
  float          *cvb;    // [128] f32: cb@wvc + bvc
  unsigned short *G;      // [9][32][128] bf16: cw_tap-folded coarse score vectors
  unsigned short *cwvT;   // [9][128 d][128 e] bf16: (cw_tap @ wvc) transposed
  unsigned short *wT;     // 8 x [128][128] bf16 transposed: wp,f1,f2,wpc,f1c,f2c,wv,wvc
  float          *out;    // [4096*10][128] f32 final output
};

// --------------- kprep: block0 = tiny precompute, blocks 1-8 = transposes ---
__global__ __launch_bounds__(256) void kprep(Par p){
  __shared__ __align__(16) unsigned char sm[66048];
  int bid = blockIdx.x, tid = threadIdx.x;
  if (bid > 0){
    // bf16 transposes via padded LDS. slots: 0 wp,1 f1w,2 f2w,3 wpc,4 f1cw,
    // 5 f2cw, 6 wv, 7 wvc
    float* lt = (float*)sm;                    // [128][129]
    int slot = bid - 1;
    const float* src;
    switch(slot){ case 0: src=p.wp;  break; case 1: src=p.f1w;  break;
                  case 2: src=p.f2w; break; case 3: src=p.wpc;  break;
                  case 4: src=p.f1cw;break; case 5: src=p.f2cw; break;
                  case 6: src=p.wv;  break; default: src=p.wvc; }
    unsigned short* dst = p.wT + slot*16384;
    for (int o=tid;o<16384;o+=256){ int k=o>>7, n=o&127; lt[n*129+k] = src[o]; }
    __syncthreads();
    for (int o=tid;o<16384;o+=256){ int n=o>>7, k=o&127; dst[o] = f2b(lt[n*129+k]); }
    return;
  }
  // ---- block 0: query LN + q-proj + score vectors + cvb ----
  float* qn = (float*)sm;                      // [10][128]
  float* qp = (float*)(sm + 5120);             // [10][128]
  unsigned short* wkb = (unsigned short*)(sm + 10240);  // [128][130]
  if (tid < 10){
    int r = tid;
    const float* row = p.query + r*128;
    float s1=0.f, s2=0.f;
    for (int c=0;c<128;c++){ float v=row[c]; s1+=v; s2+=v*v; }
    float m = s1/128.f, var = s2/128.f - m*m;
    float inv = rsqrtf(var + 1e-5f);
    const float* g  = (r<6)? p.ln1g : p.ln1cg;
    const float* bb = (r<6)? p.ln1b : p.ln1cb;
    for (int c=0;c<128;c++) qn[r*128+c] = (row[c]-m)*inv*g[c] + bb[c];
  }
  __syncthreads();
  for (int o=tid;o<1280;o+=256){
    int i=o>>7, d=o&127;
    const float* w  = (i<6)? p.wq : p.wqc;
    const float* bi = (i<6)? p.bq : p.bqc;
    float acc = bi[d];
    for (int c=0;c<128;c++) acc += qn[i*128+c]*w[c*128+d];
    qp[i*128+d]=acc;
  }
  if (tid < 128){
    int d = tid; float a = p.bvc[d];
    for (int c=0;c<128;c++) a += p.cb[c] * p.wvc[c*128+d];
    p.cvb[d] = a;
  }
  __syncthreads();
  for (int o=tid;o<16384;o+=256) wkb[(o>>7)*130 + (o&127)] = f2b(p.wk[o]);
  __syncthreads();
  for (int o=tid;o<6144;o+=256){
    int ih=o>>7, c=o&127, i=ih>>3, h=ih&7;
    float a=0.f;
    #pragma unroll
    for (int dd=0;dd<16;dd++) a += b2f(wkb[c*130 + h*16+dd]) * qp[i*128 + h*16+dd];
    p.U[ih*128+c] = f2b(0.25f*a);
  }
  __syncthreads();
  for (int o=tid;o<16384;o+=256) wkb[(o>>7)*130 + (o&127)] = f2b(p.wkc[o]);
  __syncthreads();
  for (int o=tid;o<4096;o+=256){
    int ih=o>>7, c=o&127, i=ih>>3, h=ih&7;
    float a=0.f;
    #pragma unroll
    for (int dd=0;dd<16;dd++) a += b2f(wkb[c*130 + h*16+dd]) * qp[(6+i)*128 + h*16+dd];
    p.uc[ih*128+c] = 0.25f*a;
  }
}

// ---------------- kfold: G + cwvT via MFMA (18 blocks) ----------------------
__global__ __launch_bounds__(256) void kfold(Par p){
  __shared__ alignas(16) unsigned short cwb[128*136];
  __shared__ alignas(16) unsigned short ucb[32*136];
  int bid=blockIdx.x, tid=threadIdx.x;
  int lane=tid&63, w=tid>>6, q4=lane>>4, n16=lane&15;
  int tap = (bid<9)? bid : bid-9;
  for (int o=tid;o<16384;o+=256)
    cwb[(o>>7)*136 + (o&127)] = f2b(p.cw[(size_t)tap*16384 + o]);
  if (bid < 9){
    // G[tap][ih][e] = sum_c uc[ih][c] * cw[tap][e][c]
    for (int o=tid;o<4096;o+=256) ucb[(o>>7)*136 + (o&127)] = f2b(p.uc[o]);
    __syncthreads();
    #pragma unroll
    for (int nt2=0;nt2<2;nt2++){
      int nt = w + nt2*4;
      #pragma unroll
      for (int mt=0;mt<2;mt++){
        floatx4 acc={0.f,0.f,0.f,0.f};
        #pragma unroll
        for (int ks=0;ks<4;ks++){
          mfrag a  = *reinterpret_cast<const mfrag*>(ucb + (mt*16+n16)*136 + ks*32+q4*8);
          mfrag bf = *reinterpret_cast<const mfrag*>(cwb + (nt*16+n16)*136 + ks*32+q4*8);
          acc = mfma16(a, bf, acc);
        }
        #pragma unroll
        for (int r=0;r<4;r++){
          int ih = mt*16+q4*4+r, e = nt*16+n16;
          p.G[(tap*32+ih)*128 + e] = f2b(acc[r]);
        }
      }
    }
  } else {
    // cwvT[tap][d][e] = sum_c cw[tap][e][c] * wvc[c][d]
    __syncthreads();
    const unsigned short* wvcT = p.wT + 7*16384;
    #pragma unroll 1
    for (int mt=0;mt<8;mt++){
      #pragma unroll
      for (int nt2=0;nt2<2;nt2++){
        int nt = w + nt2*4;
        floatx4 acc={0.f,0.f,0.f,0.f};
        #pragma unroll
        for (int ks=0;ks<4;ks++){
          mfrag a  = *reinterpret_cast<const mfrag*>(cwb + (mt*16+n16)*136 + ks*32+q4*8);
          mfrag bf = *reinterpret_cast<const mfrag*>(wvcT + (nt*16+n16)*128 + ks*32+q4*8);
          acc = mfma16(a, bf, acc);
        }
        us4 pk = { f2b(acc[0]), f2b(acc[1]), f2b(acc[2]), f2b(acc[3]) };
        *reinterpret_cast<us4*>(p.cwvT + ((size_t)tap*128 + nt*16+n16)*128 + mt*16 + q4*4) = pk;
      }
    }
  }
}

// ------------------------------ MAIN: one batch per block -------------------
// LDS map (81,184 B -> 2 blocks/CU):
//   [     0, 55552)  tile  : [217][128] bf16, row 216 = zeros, XOR-swizzled
//   [ 55552, 56704)  rmap  : [9 taps][64 pos] u16 PREMULT addr row*256+((row&7)<<4)
//   [ 56704, 57472)  rmapF : [6 win][64 lw]   u16 PREMULT addr
//   [ 57472, 81184)  regn  : 23,712 B phase-unioned scratch
//     sfT  @+0     [48][40] f32   F1 -> F2
//     aw   @+13056 [48][72] u16   F2 -> F3
//     rbA  @+0     [48][136] u16  F3 -> F4
//     sctT @+13056 [32][56] f32   F4&Cscore -> C2
//     ba   @+20992 [10][136] u16  F4 -> FFN (att rows, survives coarse)
//     ac   @+0     [32][72] u16   C2 -> PVc
//     vcT  @+4608  [128][64] u16 swizzled  vc -> PVc
//     FFN: xb @+0, bbq @+2720, hb @+5440 (each [10][136] u16)
__global__ __launch_bounds__(512, 4) void kmain(Par p){
  __shared__ __align__(16) unsigned char smem[81184];
  unsigned short* tile  = (unsigned short*)smem;
  unsigned short* rmap  = (unsigned short*)(smem + 55552);
  unsigned short* rmapF = (unsigned short*)(smem + 56704);
  unsigned char*  regn  = smem + 57472;
  float*          sfT   = (float*)regn;                     // [48][40]
  unsigned short* aw    = (unsigned short*)(regn + 13056);  // [48][72]
  unsigned short* rbA   = (unsigned short*)regn;            // [48][136]
  float*          sctT  = (float*)(regn + 13056);           // [32][56]
  unsigned short* ba    = (unsigned short*)(regn + 20992);  // [10][136]
  unsigned short* ac    = (unsigned short*)regn;            // [32][72]
  unsigned char*  vcT   = regn + 4608;                      // [128][64] swz
  unsigned short* xb    = (unsigned short*)regn;            // [10][136]
  unsigned short* bbq   = (unsigned short*)(regn + 2720);   // [10][136]
  unsigned short* hb    = (unsigned short*)(regn + 5440);   // [10][136]

  int tid  = threadIdx.x;
  int b    = blockIdx.x;
  int lane = tid & 63, wvx = tid >> 6;          // 8 waves
  int q4   = lane >> 4, n16 = lane & 15;
  const float* tb = p.tgt + (size_t)b*LL*128;
  const unsigned char* tB = (const unsigned char*)tile;

  auto tfragX = [&](unsigned ax, int kb)->mfrag {
    return *reinterpret_cast<const mfrag*>(
        tB + ((ax ^ (unsigned)(kb & 0x70)) + (unsigned)(kb & 0xFFFFFF8F)));
  };

  // ---- stage tile once (f32 -> bf16, swizzled), fill premult remap tables --
  {
    int c4 = tid & 31;
    unsigned c8m = (unsigned)((c4*8) & 0x70), c8l = (unsigned)((c4*8) & 0x88);
    for (int o = tid; o < 217*32; o += 512){
      int row = o >> 5;
      float4 v = make_float4(0.f,0.f,0.f,0.f);
      if (row < 216) v = *reinterpret_cast<const float4*>(tb + row*128 + (c4<<2));
      us4 wv4 = { f2b(v.x), f2b(v.y), f2b(v.z), f2b(v.w) };
      unsigned s = (unsigned)((row & 7) << 4);
      unsigned addr = (unsigned)(row*256) + ((c8m ^ s) + c8l);
      *reinterpret_cast<us4*>((unsigned char*)tile + addr) = wv4;
    }
  }
  for (int o = tid; o < 960; o += 512){
    int row;
    if (o < 576){                       // rmap[tap][pos]
      int tap = o >> 6, pos = o & 63;
      int ip = pos/9, jp = pos - ip*9;
      int r = ip*2 + tap/3 - 1, c = jp*2 + (tap%3) - 1;
      row = (pos < 54 && r >= 0 && r < 12 && c >= 0 && c < 18) ? (r*18 + c) : 216;
      rmap[o] = (unsigned short)(row*256 + ((row&7)<<4));
    } else {                            // rmapF[win][lw]
      int t = o - 576; int win = t >> 6, lw = t & 63;
      int r0 = (win/3)*6, c0 = (win%3)*6;
      row = (lw < 36) ? ((r0 + lw/6)*18 + c0 + lw%6) : 216;
      rmapF[t] = (unsigned short)(row*256 + ((row&7)<<4));
    }
  }
  __syncthreads();

  // ===================== FINE F1: all 6 windows batched =====================
  for (int task = wvx; task < 18; task += 8){
    int win = task/3, rg = task - win*3;
    unsigned ax = rmapF[win*64 + rg*16 + n16];
    floatx4 acc = {0.f,0.f,0.f,0.f};
    #pragma unroll
    for (int ks=0; ks<4; ks++){
      mfrag a = tfragX(ax, ks*64 + q4*16);
      mfrag bf = zfrag();
      if (n16 < 8) bf = *reinterpret_cast<const mfrag*>(p.U + (win*8+n16)*128 + ks*32 + q4*8);
      acc = mfma16(a, bf, acc);
    }
    if (n16 < 8){
      #pragma unroll
      for (int r=0;r<4;r++){
        int l = rg*16 + q4*4 + r;
        if (l < 36) sfT[(win*8+n16)*40 + l] = acc[r];
      }
    }
  }
  __syncthreads();
  // F2: softmax — 8 waves x 6 rows, shuffle butterflies
  {
    int l = lane;
    for (int rr=0; rr<6; rr++){
      int row = wvx*6 + rr;
      float v = (l < 36) ? sfT[row*40 + l] : -1e30f;
      float mx = v;
      #pragma unroll
      for (int m=1;m<64;m<<=1) mx = fmaxf(mx, __shfl_xor(mx, m));
      float e = (l < 36) ? __expf(v - mx) : 0.f;
      float sm = e;
      #pragma unroll
      for (int m=1;m<64;m<<=1) sm += __shfl_xor(sm, m);
      aw[row*TP2 + l] = f2b(e * (1.f/sm));
    }
  }
  __syncthreads();
  // F3: PV  rbA[win*8+h][d] = sum_l aw[..][l] * T[row(win,l)][d]
  {
    int nt = wvx;
    unsigned c2 = (unsigned)((nt*16 + n16)*2);
    unsigned c2m = c2 & 0x70u, c2l = c2 & 0x8Fu;
    for (int win=0; win<6; win++){
      floatx4 acc={0.f,0.f,0.f,0.f};
      #pragma unroll
      for (int ks=0; ks<2; ks++){
        mfrag a = zfrag();
        if (n16 < 8) a = *reinterpret_cast<const mfrag*>(aw + (win*8+n16)*TP2 + ks*32 + q4*8);
        us8 rv = *reinterpret_cast<const us8*>(rmapF + win*64 + ks*32 + q4*8);
        F8 bb;
        #pragma unroll
        for (int j=0;j<8;j++)
          bb.u[j] = *reinterpret_cast<const unsigned short*>(tB + (((unsigned)rv[j] ^ c2m) + c2l));
        acc = mfma16(a, bb.v, acc);
      }
      #pragma unroll
      for (int r=0;r<4;r++){
        int h = q4*4 + r;
        if (h < 8) rbA[(win*8+h)*TP1 + nt*16 + n16] = f2b(acc[r]);
      }
    }
  }
  __syncthreads();
  // F4 (MFMA vs wvT -> ba rows 0..5) + C-score (-> sctT), disjoint LDS
  {
    int h = wvx;
    const unsigned short* wvT = p.wT + 6*16384;
    floatx4 acc = {0.f,0.f,0.f,0.f};
    #pragma unroll
    for (int ks=0; ks<4; ks++){
      mfrag a = zfrag();
      if (n16 < 6) a = *reinterpret_cast<const mfrag*>(rbA + (n16*8+h)*TP1 + ks*32 + q4*8);
      mfrag bf = *reinterpret_cast<const mfrag*>(wvT + (h*16+n16)*128 + ks*32 + q4*8);
      acc = mfma16(a, bf, acc);
    }
    float bvd = p.bv[h*16+n16];
    #pragma unroll
    for (int r=0;r<4;r++){
      int win = q4*4 + r;
      if (win < 6) ba[win*TP1 + h*16 + n16] = f2b(acc[r] + bvd);
    }
  }
  { // C-score: 9 taps from resident tile, acc in regs
    int g = wvx >> 1, nt = wvx & 1;
    int pos = g*16 + n16;
    floatx4 acc = {0.f,0.f,0.f,0.f};
    for (int tap=0; tap<9; tap++){
      unsigned ax = rmap[tap*64 + pos];
      #pragma unroll
      for (int ks=0; ks<4; ks++){
        mfrag a = tfragX(ax, ks*64 + q4*16);
        mfrag bf = *reinterpret_cast<const mfrag*>(
            p.G + (size_t)(tap*32 + nt*16 + n16)*128 + ks*32 + q4*8);
        acc = mfma16(a, bf, acc);
      }
    }
    #pragma unroll
    for (int r=0;r<4;r++){
      int l = g*16 + q4*4 + r;
      if (l < LC) sctT[(nt*16+n16)*56 + l] = acc[r];
    }
  }
  __syncthreads();
  // C2: masked window softmax — 8 waves x 4 rows
  {
    int l = lane;
    int rl = (l < 54) ? (l/9) : 0, cl = (l < 54) ? (l - (l/9)*9) : 0;
    for (int rr=0; rr<4; rr++){
      int ih = wvx*4 + rr;
      int i = ih >> 3;
      int rA = (i>>1)*3, cA = (i&1)*4, cB = (i&1)? 9 : 4;
      bool member = (l < 54) && rl >= rA && rl < rA+3 && cl >= cA && cl < cB;
      float s = member ? sctT[ih*56 + l] : -1e30f;
      float mx = s;
      #pragma unroll
      for (int m=1;m<64;m<<=1) mx = fmaxf(mx, __shfl_xor(mx, m));
      float e = member ? __expf(s - mx) : 0.f;
      float sm = e;
      #pragma unroll
      for (int m=1;m<64;m<<=1) sm += __shfl_xor(sm, m);
      ac[ih*TP2 + l] = f2b(e * (1.f/sm));
    }
  }
  __syncthreads();
  // vc: conv-downsampled V projection vcT[d][pos], taps accumulated in regs
  {
    int dt = wvx;                       // this wave owns d-tile dt
    floatx4 va0={0.f,0.f,0.f,0.f}, va1={0.f,0.f,0.f,0.f},
            va2={0.f,0.f,0.f,0.f}, va3={0.f,0.f,0.f,0.f};
    for (int tap=0; tap<9; tap++){
      unsigned ax0 = rmap[tap*64 +  0 + n16];
      unsigned ax1 = rmap[tap*64 + 16 + n16];
      unsigned ax2 = rmap[tap*64 + 32 + n16];
      unsigned ax3 = rmap[tap*64 + 48 + n16];
      const unsigned short* cwp = p.cwvT + ((size_t)tap*128 + dt*16 + n16)*128;
      #pragma unroll
      for (int ks=0; ks<4; ks++){
        mfrag bf = *reinterpret_cast<const mfrag*>(cwp + ks*32 + q4*8);
        va0 = mfma16(tfragX(ax0, ks*64 + q4*16), bf, va0);
        va1 = mfma16(tfragX(ax1, ks*64 + q4*16), bf, va1);
        va2 = mfma16(tfragX(ax2, ks*64 + q4*16), bf, va2);
        va3 = mfma16(tfragX(ax3, ks*64 + q4*16), bf, va3);
      }
    }
    int d = dt*16 + n16;
    unsigned drow = (unsigned)(d*128), dsw = (unsigned)((d & 7) << 4);
    us4 p0 = { f2b(va0[0]), f2b(va0[1]), f2b(va0[2]), f2b(va0[3]) };
    us4 p1 = { f2b(va1[0]), f2b(va1[1]), f2b(va1[2]), f2b(va1[3]) };
    us4 p2 = { f2b(va2[0]), f2b(va2[1]), f2b(va2[2]), f2b(va2[3]) };
    us4 p3 = { f2b(va3[0]), f2b(va3[1]), f2b(va3[2]), f2b(va3[3]) };
    *reinterpret_cast<us4*>(vcT + drow + ((unsigned)( 0 + q4*8) ^ dsw)) = p0;
    *reinterpret_cast<us4*>(vcT + drow + ((unsigned)(32 + q4*8) ^ dsw)) = p1;
    *reinterpret_cast<us4*>(vcT + drow + ((unsigned)(64 + q4*8) ^ dsw)) = p2;
    *reinterpret_cast<us4*>(vcT + drow + ((unsigned)(96 + q4*8) ^ dsw)) = p3;
  }
  __syncthreads();
  // PVc: out_c[i][d] = sum_pos ac[i*8+h(d)][pos] * vcT[d][pos] -> ba rows 6..9
  {
    int nt = wvx, d = nt*16 + n16;
    unsigned dsw = (unsigned)((d & 7) << 4);
    floatx4 pa0={0.f,0.f,0.f,0.f}, pa1={0.f,0.f,0.f,0.f};
    #pragma unroll
    for (int ks=0; ks<2; ks++){
      mfrag bf = *reinterpret_cast<const mfrag*>(
          vcT + (unsigned)(d*128) + ((unsigned)(ks*64 + q4*16) ^ dsw));
      mfrag a0 = *reinterpret_cast<const mfrag*>(ac + n16*TP2        + ks*32 + q4*8);
      mfrag a1 = *reinterpret_cast<const mfrag*>(ac + (16+n16)*TP2   + ks*32 + q4*8);
      pa0 = mfma16(a0, bf, pa0);
      pa1 = mfma16(a1, bf, pa1);
    }
    float cvbd = p.cvb[d];
    float s0 = 0.f, s1 = 0.f;
    #pragma unroll
    for (int r=0;r<4;r++) if ((nt&3)==r){ s0 = pa0[r]; s1 = pa1[r]; }
    int q_lo = nt>>2, q_hi = q_lo + 2;
    if (q4 == q_lo){ ba[6*TP1 + d] = f2b(s0 + cvbd); ba[8*TP1 + d] = f2b(s1 + cvbd); }
    if (q4 == q_hi){ ba[7*TP1 + d] = f2b(s0 + cvbd); ba[9*TP1 + d] = f2b(s1 + cvbd); }
  }
  __syncthreads();
  // ============================ fused FFN ===================================
  // FFN1: x = query + att@(wp|wpc) + (bp|bpc)
  {
    int nt = wvx, d = nt*16 + n16;
    const unsigned short* wF = p.wT + 0*16384;
    const unsigned short* wC = p.wT + 3*16384;
    floatx4 aF={0.f,0.f,0.f,0.f}, aC={0.f,0.f,0.f,0.f};
    #pragma unroll
    for (int ks=0;ks<4;ks++){
      mfrag vF = zfrag(), vC = zfrag();
      if (n16 < 6)       vF = *reinterpret_cast<const mfrag*>(ba + n16*TP1 + ks*32+q4*8);
      else if (n16 < 10) vC = *reinterpret_cast<const mfrag*>(ba + n16*TP1 + ks*32+q4*8);
      mfrag BF = *reinterpret_cast<const mfrag*>(wF + (nt*16+n16)*128 + ks*32+q4*8);
      mfrag BC = *reinterpret_cast<const mfrag*>(wC + (nt*16+n16)*128 + ks*32+q4*8);
      aF = mfma16(vF, BF, aF);
      aC = mfma16(vC, BC, aC);
    }
    float bF = p.bp[d], bC = p.bpc[d];
    #pragma unroll
    for (int r=0;r<4;r++){
      int m = q4*4+r;
      if (m < 6)            xb[m*TP1+d] = f2b(aF[r] + bF + p.query[m*128+d]);
      else if (m < 10)      xb[m*TP1+d] = f2b(aC[r] + bC + p.query[m*128+d]);
    }
  }
  __syncthreads();
  // LN over x — rows spread across waves
  for (int row = wvx; row < 10; row += 8){
    bool fine = row < 6;
    const float* g2 = fine? p.ln2g : p.ln2cg;
    const float* e2 = fine? p.ln2b : p.ln2cb;
    float v0 = b2f(xb[row*TP1 + lane]), v1 = b2f(xb[row*TP1 + 64 + lane]);
    float s = v0+v1, sq = v0*v0+v1*v1;
    #pragma unroll
    for (int m=1;m<64;m<<=1){ s += __shfl_xor(s, m); sq += __shfl_xor(sq, m); }
    float mean = s*(1.f/128.f), var = sq*(1.f/128.f) - mean*mean;
    float inv = rsqrtf(var + 1e-5f);
    bbq[row*TP1 + lane]      = f2b((v0-mean)*inv*g2[lane] + e2[lane]);
    bbq[row*TP1 + 64 + lane] = f2b((v1-mean)*inv*g2[64+lane] + e2[64+lane]);
  }
  __syncthreads();
  // FFN2: h = gelu(xn@(f1|f1c) + (f1b|f1cb))
  {
    int nt = wvx, d = nt*16 + n16;
    const unsigned short* wF = p.wT + 1*16384;
    const unsigned short* wC = p.wT + 4*16384;
    floatx4 aF={0.f,0.f,0.f,0.f}, aC={0.f,0.f,0.f,0.f};
    #pragma unroll
    for (int ks=0;ks<4;ks++){
      mfrag vF = zfrag(), vC = zfrag();
      if (n16 < 6)       vF = *reinterpret_cast<const mfrag*>(bbq + n16*TP1 + ks*32+q4*8);
      else if (n16 < 10) vC = *reinterpret_cast<const mfrag*>(bbq + n16*TP1 + ks*32+q4*8);
      mfrag BF = *reinterpret_cast<const mfrag*>(wF + (nt*16+n16)*128 + ks*32+q4*8);
      mfrag BC = *reinterpret_cast<const mfrag*>(wC + (nt*16+n16)*128 + ks*32+q4*8);
      aF = mfma16(vF, BF, aF);
      aC = mfma16(vC, BC, aC);
    }
    float bF = p.f1b[d], bC = p.f1cb[d];
    #pragma unroll
    for (int r=0;r<4;r++){
      int m = q4*4+r;
      float v;
      if (m < 6) v = aF[r] + bF;
      else       v = aC[r] + bC;
      if (m < 10) hb[m*TP1+d] = f2b(0.5f*v*(1.f+erff(v*0.70710678118f)));
    }
  }
  __syncthreads();
  // FFN3: out = x + h@(f2|f2c) + (f2b|f2cb)   (f32 out)
  {
    int nt = wvx, d = nt*16 + n16;
    const unsigned short* wF = p.wT + 2*16384;
    const unsigned short* wC = p.wT + 5*16384;
    floatx4 aF={0.f,0.f,0.f,0.f}, aC={0.f,0.f,0.f,0.f};
    #pragma unroll
    for (int ks=0;ks<4;ks++){
      mfrag vF = zfrag(), vC = zfrag();
      if (n16 < 6)       vF = *reinterpret_cast<const mfrag*>(hb + n16*TP1 + ks*32+q4*8);
      else if (n16 < 10) vC = *reinterpret_cast<const mfrag*>(hb + n16*TP1 + ks*32+q4*8);
      mfrag BF = *reinterpret_cast<const mfrag*>(wF + (nt*16+n16)*128 + ks*32+q4*8);
      mfrag BC = *reinterpret_cast<const mfrag*>(wC + (nt*16+n16)*128 + ks*32+q4*8);
      aF = mfma16(vF, BF, aF);
      aC = mfma16(vC, BC, aC);
    }
    float bF = p.f2b[d], bC = p.f2cb[d];
    #pragma unroll
    for (int r=0;r<4;r++){
      int m = q4*4+r;
      if (m < 10){
        float accv = (m < 6) ? (aF[r] + bF) : (aC[r] + bC);
        p.out[((size_t)b*10 + m)*128 + d] = b2f(xb[m*TP1+d]) + accv;
      }
    }
  }
}

// ---------------------------------------------------------------------------
extern "C" void kernel_launch(void* const* d_in, const int* in_sizes, int n_in,
                              void* d_out, int out_size, void* d_ws, size_t ws_size,
                              hipStream_t stream){
  (void)in_sizes; (void)n_in; (void)out_size; (void)ws_size;
  Par p;
  p.query=(const float*)d_in[0];  p.tgt  =(const float*)d_in[1];
  p.ln1g =(const float*)d_in[2];  p.ln1b =(const float*)d_in[3];
  p.ln2g =(const float*)d_in[4];  p.ln2b =(const float*)d_in[5];
  p.wq   =(const float*)d_in[6];  p.bq   =(const float*)d_in[7];
  p.wk   =(const float*)d_in[8];  /* bk d_in[9] unused (softmax-invariant) */
  p.wv   =(const float*)d_in[10]; p.bv   =(const float*)d_in[11];
  p.wp   =(const float*)d_in[12]; p.bp   =(const float*)d_in[13];
  p.f1w  =(const float*)d_in[14]; p.f1b  =(const float*)d_in[15];
  p.f2w  =(const float*)d_in[16]; p.f2b  =(const float*)d_in[17];
  p.cw   =(const float*)d_in[18]; p.cb   =(const float*)d_in[19];
  p.ln1cg=(const float*)d_in[20]; p.ln1cb=(const float*)d_in[21];
  p.ln2cg=(const float*)d_in[22]; p.ln2cb=(const float*)d_in[23];
  p.wqc  =(const float*)d_in[24]; p.bqc  =(const float*)d_in[25];
  p.wkc  =(const float*)d_in[26]; /* bkc d_in[27] unused */
  p.wvc  =(const float*)d_in[28]; p.bvc  =(const float*)d_in[29];
  p.wpc  =(const float*)d_in[30]; p.bpc  =(const float*)d_in[31];
  p.f1cw =(const float*)d_in[32]; p.f1cb =(const float*)d_in[33];
  p.f2cw =(const float*)d_in[34]; p.f2cb =(const float*)d_in[35];
  char* ws = (char*)d_ws;
  p.U    = (unsigned short*)(ws + 0);        //  12,288 B
  p.uc   = (float*)        (ws + 16384);     //  16,384 B
  p.cvb  = (float*)        (ws + 32768);     //     512 B
  p.G    = (unsigned short*)(ws + 33280);    //  73,728 B -> 107,008
  p.cwvT = (unsigned short*)(ws + 107008);   // 294,912 B -> 401,920
  p.wT   = (unsigned short*)(ws + 401920);   // 8 x 32,768 B -> 664,064
  p.out  = (float*)d_out;

  kprep<<<dim3(9),    dim3(256), 0, stream>>>(p);
  kfold<<<dim3(18),   dim3(256), 0, stream>>>(p);
  kmain<<<dim3(4096), dim3(512), 0, stream>>>(p);
}

// Round 4
// 998.666 us; speedup vs baseline: 1.1143x; 1.1143x over previous
//
#include <hip/hip_runtime.h>
#include <math.h>

// ---------------------------------------------------------------------------
// CrossAttentionLayer_convk3s2 — FP32 in/out, bf16 MFMA internally.
// R4: - vc phase balanced split (pos-half x d-quarter per wave): tile A-reads
//       halved (1152->576 KB/block), conflicts down; B-reads move to L2 as
//       coalesced 1KB frag-linear loads.
//     - ALL global MFMA B-operands (U, G, cwvT, wT) stored in frag-linear
//       layout (block*512 + lane*8) by kprep/kfold -> every B-load is one
//       coalesced transaction. F1's n16<8 branch removed (zero-padded U).
//     - kprep: coarse uc prep moved to its own block (shorter serial chain).
// Launches: kprep(10) -> kfold(18) -> kmain(4096).
// ---------------------------------------------------------------------------

typedef short   mfrag  __attribute__((ext_vector_type(8)));   // 8 x bf16 bits
typedef float   floatx4 __attribute__((ext_vector_type(4)));
typedef unsigned short us4 __attribute__((ext_vector_type(4)));
typedef unsigned short us8 __attribute__((ext_vector_type(8)));

#define LL   216     // 12*18 tokens
#define LC   54      // 6*9 coarse positions
#define TP1  136     // pitch (ushorts) for 128-col LDS rows (272B)
#define TP2  72      // pitch (ushorts) for 64-col LDS rows

__device__ __forceinline__ float b2f(unsigned short u){
  return __uint_as_float(((unsigned int)u) << 16);
}
__device__ __forceinline__ unsigned short f2b(float f){
  unsigned int x = __float_as_uint(f);
  return (unsigned short)((x + 0x7fffu + ((x >> 16) & 1u)) >> 16);
}
__device__ __forceinline__ floatx4 mfma16(mfrag a, mfrag b, floatx4 c){
  return __builtin_amdgcn_mfma_f32_16x16x32_bf16(a, b, c, 0, 0, 0);
}
__device__ __forceinline__ mfrag zfrag(){ mfrag z = {0,0,0,0,0,0,0,0}; return z; }

union F8 { unsigned short u[8]; mfrag v; };

// frag-linear index helper (producer side): element (n,k) of a [128|32][128]
// B-matrix whose consumer reads mfrag at block(nt,ks)*512 + lane*8:
//   idx = (blockbase + (n>>4)*4 + (k>>5))*512 + ((k>>3)&3)*128 + (n&15)*8 + (k&7)

struct Par {
  const float *query,*tgt,*ln1g,*ln1b,*ln2g,*ln2b,*wq,*bq,*wk,*wv,*bv,
              *wp,*bp,*f1w,*f1b,*f2w,*f2b,*cw,*cb;
  const float *ln1cg,*ln1cb,*ln2cg,*ln2cb,*wqc,*bqc,*wkc,*wvc,*bvc,
              *wpc,*bpc,*f1cw,*f1cb,*f2cw,*f2cb;
  unsigned short *U;      // frag-linear [6 win][4 ks] blocks (rows 8-15 zero)
  float          *uc;     // [32][128] f32: coarse score vectors pre-conv-fold
  float          *cvb;    // [128] f32: cb@wvc + bvc
  unsigned short *G;      // frag-linear [(tap*2+mt)*4+ks] blocks
  unsigned short *cwvT;   // frag-linear [(tap*8+dt)*4+ks] blocks
  unsigned short *wT;     // frag-linear 8 slots x [8 nt][4 ks] blocks
  float          *out;    // [4096*10][128] f32 final output
};

// --------------- kprep: 0 = fine prep, 1-8 = transposes, 9 = coarse prep ----
__global__ __launch_bounds__(256) void kprep(Par p){
  __shared__ __align__(16) unsigned char sm[66048];
  int bid = blockIdx.x, tid = threadIdx.x;
  if (bid >= 1 && bid <= 8){
    // bf16 transposes via padded LDS -> frag-linear global layout.
    // slots: 0 wp,1 f1w,2 f2w,3 wpc,4 f1cw,5 f2cw,6 wv,7 wvc
    float* lt = (float*)sm;                    // [128][129]
    int slot = bid - 1;
    const float* src;
    switch(slot){ case 0: src=p.wp;  break; case 1: src=p.f1w;  break;
                  case 2: src=p.f2w; break; case 3: src=p.wpc;  break;
                  case 4: src=p.f1cw;break; case 5: src=p.f2cw; break;
                  case 6: src=p.wv;  break; default: src=p.wvc; }
    for (int o=tid;o<16384;o+=256){ int k=o>>7, n=o&127; lt[n*129+k] = src[o]; }
    __syncthreads();
    for (int o=tid;o<16384;o+=256){
      int n=o>>7, k=o&127;
      int idx = ((slot*8 + (n>>4))*4 + (k>>5))*512
              + ((k>>3)&3)*128 + (n&15)*8 + (k&7);
      p.wT[idx] = f2b(lt[n*129+k]);
    }
    return;
  }
  float* qn = (float*)sm;                      // [10][128]
  float* qp = (float*)(sm + 5120);             // [10][128]
  unsigned short* wkb = (unsigned short*)(sm + 10240);  // [128][130]
  if (bid == 0){
    // ---- fine prep: LN rows 0-5, q-proj, cvb, U (frag-linear) ----
    if (tid < 6){
      int r = tid;
      const float* row = p.query + r*128;
      float s1=0.f, s2=0.f;
      for (int c=0;c<128;c++){ float v=row[c]; s1+=v; s2+=v*v; }
      float m = s1/128.f, var = s2/128.f - m*m;
      float inv = rsqrtf(var + 1e-5f);
      for (int c=0;c<128;c++) qn[r*128+c] = (row[c]-m)*inv*p.ln1g[c] + p.ln1b[c];
    }
    for (int o=tid;o<12288;o+=256) p.U[o] = 0;   // zero-pad frag rows 8-15
    if (tid < 128){
      int d = tid; float a = p.bvc[d];
      for (int c=0;c<128;c++) a += p.cb[c] * p.wvc[c*128+d];
      p.cvb[d] = a;
    }
    __syncthreads();
    for (int o=tid;o<768;o+=256){
      int i=o>>7, d=o&127;
      float acc = p.bq[d];
      for (int c=0;c<128;c++) acc += qn[i*128+c]*p.wq[c*128+d];
      qp[i*128+d]=acc;
    }
    __syncthreads();
    for (int o=tid;o<16384;o+=256) wkb[(o>>7)*130 + (o&127)] = f2b(p.wk[o]);
    __syncthreads();
    for (int o=tid;o<6144;o+=256){
      int ih=o>>7, c=o&127, i=ih>>3, h=ih&7;
      float a=0.f;
      #pragma unroll
      for (int dd=0;dd<16;dd++) a += b2f(wkb[c*130 + h*16+dd]) * qp[i*128 + h*16+dd];
      int idx = (i*4 + (c>>5))*512 + ((c>>3)&3)*128 + h*8 + (c&7);
      p.U[idx] = f2b(0.25f*a);
    }
  } else {
    // ---- coarse prep (bid==9): LN rows 6-9, q-proj, uc ----
    if (tid >= 6 && tid < 10){
      int r = tid;
      const float* row = p.query + r*128;
      float s1=0.f, s2=0.f;
      for (int c=0;c<128;c++){ float v=row[c]; s1+=v; s2+=v*v; }
      float m = s1/128.f, var = s2/128.f - m*m;
      float inv = rsqrtf(var + 1e-5f);
      for (int c=0;c<128;c++) qn[r*128+c] = (row[c]-m)*inv*p.ln1cg[c] + p.ln1cb[c];
    }
    __syncthreads();
    for (int o=tid;o<512;o+=256){
      int i=6+(o>>7), d=o&127;
      float acc = p.bqc[d];
      for (int c=0;c<128;c++) acc += qn[i*128+c]*p.wqc[c*128+d];
      qp[i*128+d]=acc;
    }
    __syncthreads();
    for (int o=tid;o<16384;o+=256) wkb[(o>>7)*130 + (o&127)] = f2b(p.wkc[o]);
    __syncthreads();
    for (int o=tid;o<4096;o+=256){
      int ih=o>>7, c=o&127, i=ih>>3, h=ih&7;
      float a=0.f;
      #pragma unroll
      for (int dd=0;dd<16;dd++) a += b2f(wkb[c*130 + h*16+dd]) * qp[(6+i)*128 + h*16+dd];
      p.uc[ih*128+c] = 0.25f*a;
    }
  }
}

// ---------------- kfold: G + cwvT via MFMA (18 blocks), frag-linear stores --
__global__ __launch_bounds__(256) void kfold(Par p){
  __shared__ alignas(16) unsigned short cwb[128*136];
  __shared__ alignas(16) unsigned short ucb[32*136];
  int bid=blockIdx.x, tid=threadIdx.x;
  int lane=tid&63, w=tid>>6, q4=lane>>4, n16=lane&15;
  int tap = (bid<9)? bid : bid-9;
  for (int o=tid;o<16384;o+=256)
    cwb[(o>>7)*136 + (o&127)] = f2b(p.cw[(size_t)tap*16384 + o]);
  if (bid < 9){
    // G[tap][ih][e] = sum_c uc[ih][c] * cw[tap][e][c]
    for (int o=tid;o<4096;o+=256) ucb[(o>>7)*136 + (o&127)] = f2b(p.uc[o]);
    __syncthreads();
    #pragma unroll
    for (int nt2=0;nt2<2;nt2++){
      int nt = w + nt2*4;
      #pragma unroll
      for (int mt=0;mt<2;mt++){
        floatx4 acc={0.f,0.f,0.f,0.f};
        #pragma unroll
        for (int ks=0;ks<4;ks++){
          mfrag a  = *reinterpret_cast<const mfrag*>(ucb + (mt*16+n16)*136 + ks*32+q4*8);
          mfrag bf = *reinterpret_cast<const mfrag*>(cwb + (nt*16+n16)*136 + ks*32+q4*8);
          acc = mfma16(a, bf, acc);
        }
        #pragma unroll
        for (int r=0;r<4;r++){
          // elem (ih = mt*16+q4*4+r, e = nt*16+n16) -> frag-linear
          int idx = ((tap*2+mt)*4 + (nt>>1))*512
                  + ((nt&1)*2 + (n16>>3))*128 + (q4*4+r)*8 + (n16&7);
          p.G[idx] = f2b(acc[r]);
        }
      }
    }
  } else {
    // cwvT[tap]: elem (d, e) = sum_c cw[tap][e][c] * wvc[c][d]
    __syncthreads();
    #pragma unroll 1
    for (int mt=0;mt<8;mt++){
      #pragma unroll
      for (int nt2=0;nt2<2;nt2++){
        int nt = w + nt2*4;
        floatx4 acc={0.f,0.f,0.f,0.f};
        #pragma unroll
        for (int ks=0;ks<4;ks++){
          mfrag a  = *reinterpret_cast<const mfrag*>(cwb + (mt*16+n16)*136 + ks*32+q4*8);
          mfrag bf = *reinterpret_cast<const mfrag*>(p.wT + ((7*8+nt)*4+ks)*512 + lane*8);
          acc = mfma16(a, bf, acc);
        }
        // elem (e = mt*16+q4*4+r, d = nt*16+n16) -> frag-linear, us4 over r
        size_t base = (size_t)((tap*8+nt)*4 + (mt>>1))*512
                    + ((mt&1)*2 + (q4>>1))*128 + n16*8 + (q4&1)*4;
        us4 pk = { f2b(acc[0]), f2b(acc[1]), f2b(acc[2]), f2b(acc[3]) };
        *reinterpret_cast<us4*>(p.cwvT + base) = pk;
      }
    }
  }
}

// ------------------------------ MAIN: one batch per block -------------------
// LDS map (81,184 B -> 2 blocks/CU): same as R3.
__global__ __launch_bounds__(512, 4) void kmain(Par p){
  __shared__ __align__(16) unsigned char smem[81184];
  unsigned short* tile  = (unsigned short*)smem;
  unsigned short* rmap  = (unsigned short*)(smem + 55552);
  unsigned short* rmapF = (unsigned short*)(smem + 56704);
  unsigned char*  regn  = smem + 57472;
  float*          sfT   = (float*)regn;                     // [48][40]
  unsigned short* aw    = (unsigned short*)(regn + 13056);  // [48][72]
  unsigned short* rbA   = (unsigned short*)regn;            // [48][136]
  float*          sctT  = (float*)(regn + 13056);           // [32][56]
  unsigned short* ba    = (unsigned short*)(regn + 20992);  // [10][136]
  unsigned short* ac    = (unsigned short*)regn;            // [32][72]
  unsigned char*  vcT   = regn + 4608;                      // [128][64] swz
  unsigned short* xb    = (unsigned short*)regn;            // [10][136]
  unsigned short* bbq   = (unsigned short*)(regn + 2720);   // [10][136]
  unsigned short* hb    = (unsigned short*)(regn + 5440);   // [10][136]

  int tid  = threadIdx.x;
  int b    = blockIdx.x;
  int lane = tid & 63, wvx = tid >> 6;          // 8 waves
  int q4   = lane >> 4, n16 = lane & 15;
  const float* tb = p.tgt + (size_t)b*LL*128;
  const unsigned char* tB = (const unsigned char*)tile;

  auto tfragX = [&](unsigned ax, int kb)->mfrag {
    return *reinterpret_cast<const mfrag*>(
        tB + ((ax ^ (unsigned)(kb & 0x70)) + (unsigned)(kb & 0xFFFFFF8F)));
  };

  // ---- stage tile once (f32 -> bf16, swizzled), fill premult remap tables --
  {
    int c4 = tid & 31;
    unsigned c8m = (unsigned)((c4*8) & 0x70), c8l = (unsigned)((c4*8) & 0x88);
    for (int o = tid; o < 217*32; o += 512){
      int row = o >> 5;
      float4 v = make_float4(0.f,0.f,0.f,0.f);
      if (row < 216) v = *reinterpret_cast<const float4*>(tb + row*128 + (c4<<2));
      us4 wv4 = { f2b(v.x), f2b(v.y), f2b(v.z), f2b(v.w) };
      unsigned s = (unsigned)((row & 7) << 4);
      unsigned addr = (unsigned)(row*256) + ((c8m ^ s) + c8l);
      *reinterpret_cast<us4*>((unsigned char*)tile + addr) = wv4;
    }
  }
  for (int o = tid; o < 960; o += 512){
    int row;
    if (o < 576){                       // rmap[tap][pos]
      int tap = o >> 6, pos = o & 63;
      int ip = pos/9, jp = pos - ip*9;
      int r = ip*2 + tap/3 - 1, c = jp*2 + (tap%3) - 1;
      row = (pos < 54 && r >= 0 && r < 12 && c >= 0 && c < 18) ? (r*18 + c) : 216;
      rmap[o] = (unsigned short)(row*256 + ((row&7)<<4));
    } else {                            // rmapF[win][lw]
      int t = o - 576; int win = t >> 6, lw = t & 63;
      int r0 = (win/3)*6, c0 = (win%3)*6;
      row = (lw < 36) ? ((r0 + lw/6)*18 + c0 + lw%6) : 216;
      rmapF[t] = (unsigned short)(row*256 + ((row&7)<<4));
    }
  }
  __syncthreads();

  // ===================== FINE F1: all 6 windows batched =====================
  for (int task = wvx; task < 18; task += 8){
    int win = task/3, rg = task - win*3;
    unsigned ax = rmapF[win*64 + rg*16 + n16];
    floatx4 acc = {0.f,0.f,0.f,0.f};
    #pragma unroll
    for (int ks=0; ks<4; ks++){
      mfrag a = tfragX(ax, ks*64 + q4*16);
      mfrag bf = *reinterpret_cast<const mfrag*>(p.U + (win*4+ks)*512 + lane*8);
      acc = mfma16(a, bf, acc);
    }
    if (n16 < 8){
      #pragma unroll
      for (int r=0;r<4;r++){
        int l = rg*16 + q4*4 + r;
        if (l < 36) sfT[(win*8+n16)*40 + l] = acc[r];
      }
    }
  }
  __syncthreads();
  // F2: softmax — 8 waves x 6 rows, shuffle butterflies
  {
    int l = lane;
    for (int rr=0; rr<6; rr++){
      int row = wvx*6 + rr;
      float v = (l < 36) ? sfT[row*40 + l] : -1e30f;
      float mx = v;
      #pragma unroll
      for (int m=1;m<64;m<<=1) mx = fmaxf(mx, __shfl_xor(mx, m));
      float e = (l < 36) ? __expf(v - mx) : 0.f;
      float sm = e;
      #pragma unroll
      for (int m=1;m<64;m<<=1) sm += __shfl_xor(sm, m);
      aw[row*TP2 + l] = f2b(e * (1.f/sm));
    }
  }
  __syncthreads();
  // F3: PV  rbA[win*8+h][d] = sum_l aw[..][l] * T[row(win,l)][d]
  {
    int nt = wvx;
    unsigned c2 = (unsigned)((nt*16 + n16)*2);
    unsigned c2m = c2 & 0x70u, c2l = c2 & 0x8Fu;
    for (int win=0; win<6; win++){
      floatx4 acc={0.f,0.f,0.f,0.f};
      #pragma unroll
      for (int ks=0; ks<2; ks++){
        mfrag a = zfrag();
        if (n16 < 8) a = *reinterpret_cast<const mfrag*>(aw + (win*8+n16)*TP2 + ks*32 + q4*8);
        us8 rv = *reinterpret_cast<const us8*>(rmapF + win*64 + ks*32 + q4*8);
        F8 bb;
        #pragma unroll
        for (int j=0;j<8;j++)
          bb.u[j] = *reinterpret_cast<const unsigned short*>(tB + (((unsigned)rv[j] ^ c2m) + c2l));
        acc = mfma16(a, bb.v, acc);
      }
      #pragma unroll
      for (int r=0;r<4;r++){
        int h = q4*4 + r;
        if (h < 8) rbA[(win*8+h)*TP1 + nt*16 + n16] = f2b(acc[r]);
      }
    }
  }
  __syncthreads();
  // F4 (MFMA vs wvT -> ba rows 0..5) + C-score (-> sctT), disjoint LDS
  {
    int h = wvx;
    floatx4 acc = {0.f,0.f,0.f,0.f};
    #pragma unroll
    for (int ks=0; ks<4; ks++){
      mfrag a = zfrag();
      if (n16 < 6) a = *reinterpret_cast<const mfrag*>(rbA + (n16*8+h)*TP1 + ks*32 + q4*8);
      mfrag bf = *reinterpret_cast<const mfrag*>(p.wT + ((6*8+h)*4+ks)*512 + lane*8);
      acc = mfma16(a, bf, acc);
    }
    float bvd = p.bv[h*16+n16];
    #pragma unroll
    for (int r=0;r<4;r++){
      int win = q4*4 + r;
      if (win < 6) ba[win*TP1 + h*16 + n16] = f2b(acc[r] + bvd);
    }
  }
  { // C-score: 9 taps from resident tile, acc in regs
    int g = wvx >> 1, nt = wvx & 1;
    int pos = g*16 + n16;
    floatx4 acc = {0.f,0.f,0.f,0.f};
    for (int tap=0; tap<9; tap++){
      unsigned ax = rmap[tap*64 + pos];
      #pragma unroll
      for (int ks=0; ks<4; ks++){
        mfrag a = tfragX(ax, ks*64 + q4*16);
        mfrag bf = *reinterpret_cast<const mfrag*>(p.G + ((tap*2+nt)*4+ks)*512 + lane*8);
        acc = mfma16(a, bf, acc);
      }
    }
    #pragma unroll
    for (int r=0;r<4;r++){
      int l = g*16 + q4*4 + r;
      if (l < LC) sctT[(nt*16+n16)*56 + l] = acc[r];
    }
  }
  __syncthreads();
  // C2: masked window softmax — 8 waves x 4 rows
  {
    int l = lane;
    int rl = (l < 54) ? (l/9) : 0, cl = (l < 54) ? (l - (l/9)*9) : 0;
    for (int rr=0; rr<4; rr++){
      int ih = wvx*4 + rr;
      int i = ih >> 3;
      int rA = (i>>1)*3, cA = (i&1)*4, cB = (i&1)? 9 : 4;
      bool member = (l < 54) && rl >= rA && rl < rA+3 && cl >= cA && cl < cB;
      float s = member ? sctT[ih*56 + l] : -1e30f;
      float mx = s;
      #pragma unroll
      for (int m=1;m<64;m<<=1) mx = fmaxf(mx, __shfl_xor(mx, m));
      float e = member ? __expf(s - mx) : 0.f;
      float sm = e;
      #pragma unroll
      for (int m=1;m<64;m<<=1) sm += __shfl_xor(sm, m);
      ac[ih*TP2 + l] = f2b(e * (1.f/sm));
    }
  }
  __syncthreads();
  // vc: conv-downsampled V projection vcT[d][pos]; balanced wave split:
  // wave = (g2 = wvx&1: pos-half, dq = wvx>>1: d-quarter); taps in regs.
  {
    int g2 = wvx & 1, dq = wvx >> 1;
    floatx4 a00={0.f,0.f,0.f,0.f}, a01={0.f,0.f,0.f,0.f},
            a10={0.f,0.f,0.f,0.f}, a11={0.f,0.f,0.f,0.f};
    for (int tap=0; tap<9; tap++){
      unsigned axA = rmap[tap*64 + (g2*2+0)*16 + n16];
      unsigned axB = rmap[tap*64 + (g2*2+1)*16 + n16];
      const unsigned short* c0 = p.cwvT + (size_t)((tap*8 + dq*2+0)*4)*512;
      const unsigned short* c1 = p.cwvT + (size_t)((tap*8 + dq*2+1)*4)*512;
      #pragma unroll
      for (int ks=0; ks<4; ks++){
        mfrag fa0 = tfragX(axA, ks*64 + q4*16);
        mfrag fa1 = tfragX(axB, ks*64 + q4*16);
        mfrag fb0 = *reinterpret_cast<const mfrag*>(c0 + ks*512 + lane*8);
        mfrag fb1 = *reinterpret_cast<const mfrag*>(c1 + ks*512 + lane*8);
        a00 = mfma16(fa0, fb0, a00);
        a01 = mfma16(fa0, fb1, a01);
        a10 = mfma16(fa1, fb0, a10);
        a11 = mfma16(fa1, fb1, a11);
      }
    }
    #pragma unroll
    for (int pg=0; pg<2; pg++){
      #pragma unroll
      for (int dt2=0; dt2<2; dt2++){
        floatx4 av = pg ? (dt2 ? a11 : a10) : (dt2 ? a01 : a00);
        int d = (dq*2+dt2)*16 + n16;
        int pos0 = (g2*2+pg)*16 + q4*4;
        unsigned addr = (unsigned)(d*128)
                      + (((unsigned)(pos0*2)) ^ ((unsigned)((d&7)<<4)));
        us4 pk = { f2b(av[0]), f2b(av[1]), f2b(av[2]), f2b(av[3]) };
        *reinterpret_cast<us4*>(vcT + addr) = pk;
      }
    }
  }
  __syncthreads();
  // PVc: out_c[i][d] = sum_pos ac[i*8+h(d)][pos] * vcT[d][pos] -> ba rows 6..9
  {
    int nt = wvx, d = nt*16 + n16;
    unsigned dsw = (unsigned)((d & 7) << 4);
    floatx4 pa0={0.f,0.f,0.f,0.f}, pa1={0.f,0.f,0.f,0.f};
    #pragma unroll
    for (int ks=0; ks<2; ks++){
      mfrag bf = *reinterpret_cast<const mfrag*>(
          vcT + (unsigned)(d*128) + ((unsigned)(ks*64 + q4*16) ^ dsw));
      mfrag fa0 = *reinterpret_cast<const mfrag*>(ac + n16*TP2        + ks*32 + q4*8);
      mfrag fa1 = *reinterpret_cast<const mfrag*>(ac + (16+n16)*TP2   + ks*32 + q4*8);
      pa0 = mfma16(fa0, bf, pa0);
      pa1 = mfma16(fa1, bf, pa1);
    }
    float cvbd = p.cvb[d];
    float s0 = 0.f, s1 = 0.f;
    #pragma unroll
    for (int r=0;r<4;r++) if ((nt&3)==r){ s0 = pa0[r]; s1 = pa1[r]; }
    int q_lo = nt>>2, q_hi = q_lo + 2;
    if (q4 == q_lo){ ba[6*TP1 + d] = f2b(s0 + cvbd); ba[8*TP1 + d] = f2b(s1 + cvbd); }
    if (q4 == q_hi){ ba[7*TP1 + d] = f2b(s0 + cvbd); ba[9*TP1 + d] = f2b(s1 + cvbd); }
  }
  __syncthreads();
  // ============================ fused FFN ===================================
  // FFN1: x = query + att@(wp|wpc) + (bp|bpc)
  {
    int nt = wvx, d = nt*16 + n16;
    floatx4 aF={0.f,0.f,0.f,0.f}, aC={0.f,0.f,0.f,0.f};
    #pragma unroll
    for (int ks=0;ks<4;ks++){
      mfrag vF = zfrag(), vC = zfrag();
      if (n16 < 6)       vF = *reinterpret_cast<const mfrag*>(ba + n16*TP1 + ks*32+q4*8);
      else if (n16 < 10) vC = *reinterpret_cast<const mfrag*>(ba + n16*TP1 + ks*32+q4*8);
      mfrag BF = *reinterpret_cast<const mfrag*>(p.wT + ((0*8+nt)*4+ks)*512 + lane*8);
      mfrag BC = *reinterpret_cast<const mfrag*>(p.wT + ((3*8+nt)*4+ks)*512 + lane*8);
      aF = mfma16(vF, BF, aF);
      aC = mfma16(vC, BC, aC);
    }
    float bF = p.bp[d], bC = p.bpc[d];
    #pragma unroll
    for (int r=0;r<4;r++){
      int m = q4*4+r;
      if (m < 6)            xb[m*TP1+d] = f2b(aF[r] + bF + p.query[m*128+d]);
      else if (m < 10)      xb[m*TP1+d] = f2b(aC[r] + bC + p.query[m*128+d]);
    }
  }
  __syncthreads();
  // LN over x — rows spread across waves
  for (int row = wvx; row < 10; row += 8){
    bool fine = row < 6;
    const float* g2v = fine? p.ln2g : p.ln2cg;
    const float* e2 = fine? p.ln2b : p.ln2cb;
    float v0 = b2f(xb[row*TP1 + lane]), v1 = b2f(xb[row*TP1 + 64 + lane]);
    float s = v0+v1, sq = v0*v0+v1*v1;
    #pragma unroll
    for (int m=1;m<64;m<<=1){ s += __shfl_xor(s, m); sq += __shfl_xor(sq, m); }
    float mean = s*(1.f/128.f), var = sq*(1.f/128.f) - mean*mean;
    float inv = rsqrtf(var + 1e-5f);
    bbq[row*TP1 + lane]      = f2b((v0-mean)*inv*g2v[lane] + e2[lane]);
    bbq[row*TP1 + 64 + lane] = f2b((v1-mean)*inv*g2v[64+lane] + e2[64+lane]);
  }
  __syncthreads();
  // FFN2: h = gelu(xn@(f1|f1c) + (f1b|f1cb))
  {
    int nt = wvx, d = nt*16 + n16;
    floatx4 aF={0.f,0.f,0.f,0.f}, aC={0.f,0.f,0.f,0.f};
    #pragma unroll
    for (int ks=0;ks<4;ks++){
      mfrag vF = zfrag(), vC = zfrag();
      if (n16 < 6)       vF = *reinterpret_cast<const mfrag*>(bbq + n16*TP1 + ks*32+q4*8);
      else if (n16 < 10) vC = *reinterpret_cast<const mfrag*>(bbq + n16*TP1 + ks*32+q4*8);
      mfrag BF = *reinterpret_cast<const mfrag*>(p.wT + ((1*8+nt)*4+ks)*512 + lane*8);
      mfrag BC = *reinterpret_cast<const mfrag*>(p.wT + ((4*8+nt)*4+ks)*512 + lane*8);
      aF = mfma16(vF, BF, aF);
      aC = mfma16(vC, BC, aC);
    }
    float bF = p.f1b[d], bC = p.f1cb[d];
    #pragma unroll
    for (int r=0;r<4;r++){
      int m = q4*4+r;
      float v;
      if (m < 6) v = aF[r] + bF;
      else       v = aC[r] + bC;
      if (m < 10) hb[m*TP1+d] = f2b(0.5f*v*(1.f+erff(v*0.70710678118f)));
    }
  }
  __syncthreads();
  // FFN3: out = x + h@(f2|f2c) + (f2b|f2cb)   (f32 out)
  {
    int nt = wvx, d = nt*16 + n16;
    floatx4 aF={0.f,0.f,0.f,0.f}, aC={0.f,0.f,0.f,0.f};
    #pragma unroll
    for (int ks=0;ks<4;ks++){
      mfrag vF = zfrag(), vC = zfrag();
      if (n16 < 6)       vF = *reinterpret_cast<const mfrag*>(hb + n16*TP1 + ks*32+q4*8);
      else if (n16 < 10) vC = *reinterpret_cast<const mfrag*>(hb + n16*TP1 + ks*32+q4*8);
      mfrag BF = *reinterpret_cast<const mfrag*>(p.wT + ((2*8+nt)*4+ks)*512 + lane*8);
      mfrag BC = *reinterpret_cast<const mfrag*>(p.wT + ((5*8+nt)*4+ks)*512 + lane*8);
      aF = mfma16(vF, BF, aF);
      aC = mfma16(vC, BC, aC);
    }
    float bF = p.f2b[d], bC = p.f2cb[d];
    #pragma unroll
    for (int r=0;r<4;r++){
      int m = q4*4+r;
      if (m < 10){
        float accv = (m < 6) ? (aF[r] + bF) : (aC[r] + bC);
        p.out[((size_t)b*10 + m)*128 + d] = b2f(xb[m*TP1+d]) + accv;
      }
    }
  }
}

// ---------------------------------------------------------------------------
extern "C" void kernel_launch(void* const* d_in, const int* in_sizes, int n_in,
                              void* d_out, int out_size, void* d_ws, size_t ws_size,
                              hipStream_t stream){
  (void)in_sizes; (void)n_in; (void)out_size; (void)ws_size;
  Par p;
  p.query=(const float*)d_in[0];  p.tgt  =(const float*)d_in[1];
  p.ln1g =(const float*)d_in[2];  p.ln1b =(const float*)d_in[3];
  p.ln2g =(const float*)d_in[4];  p.ln2b =(const float*)d_in[5];
  p.wq   =(const float*)d_in[6];  p.bq   =(const float*)d_in[7];
  p.wk   =(const float*)d_in[8];  /* bk d_in[9] unused (softmax-invariant) */
  p.wv   =(const float*)d_in[10]; p.bv   =(const float*)d_in[11];
  p.wp   =(const float*)d_in[12]; p.bp   =(const float*)d_in[13];
  p.f1w  =(const float*)d_in[14]; p.f1b  =(const float*)d_in[15];
  p.f2w  =(const float*)d_in[16]; p.f2b  =(const float*)d_in[17];
  p.cw   =(const float*)d_in[18]; p.cb   =(const float*)d_in[19];
  p.ln1cg=(const float*)d_in[20]; p.ln1cb=(const float*)d_in[21];
  p.ln2cg=(const float*)d_in[22]; p.ln2cb=(const float*)d_in[23];
  p.wqc  =(const float*)d_in[24]; p.bqc  =(const float*)d_in[25];
  p.wkc  =(const float*)d_in[26]; /* bkc d_in[27] unused */
  p.wvc  =(const float*)d_in[28]; p.bvc  =(const float*)d_in[29];
  p.wpc  =(const float*)d_in[30]; p.bpc  =(const float*)d_in[31];
  p.f1cw =(const float*)d_in[32]; p.f1cb =(const float*)d_in[33];
  p.f2cw =(const float*)d_in[34]; p.f2cb =(const float*)d_in[35];
  char* ws = (char*)d_ws;
  p.U    = (unsigned short*)(ws + 0);        //  24,576 B
  p.uc   = (float*)        (ws + 24576);     //  16,384 B -> 40,960
  p.cvb  = (float*)        (ws + 40960);     //     512 B -> 41,472
  p.G    = (unsigned short*)(ws + 41472);    //  73,728 B -> 115,200
  p.cwvT = (unsigned short*)(ws + 115200);   // 294,912 B -> 410,112
  p.wT   = (unsigned short*)(ws + 410112);   // 262,144 B -> 672,256
  p.out  = (float*)d_out;

  kprep<<<dim3(10),   dim3(256), 0, stream>>>(p);
  kfold<<<dim3(18),   dim3(256), 0, stream>>>(p);
  kmain<<<dim3(4096), dim3(512), 0, stream>>>(p);
}